// Round 4
// baseline (1487.496 us; speedup 1.0000x reference)
//
#include <hip/hip_runtime.h>
#include <hip/hip_bf16.h>
#include <cmath>

// Problem constants
#define TT 1024
#define HH 8
#define KVHN 4

// ---------------------------------------------------------------------------
// K1: fused QKV projection + RoPE.
// Grid: (B*T)/8 = 256 blocks, 256 threads. Each block does 8 rows of x.
// Outputs: Q (B*H,T,HD), K (B*KVH,T,HD), V (B*KVH,T,HD)  [head-major]
// ---------------------------------------------------------------------------
__global__ __launch_bounds__(256) void qkv_rope_kernel(
    const float* __restrict__ x, const float* __restrict__ cosb,
    const float* __restrict__ sinb, const float* __restrict__ Wq,
    const float* __restrict__ Wk, const float* __restrict__ Wv,
    float* __restrict__ Q, float* __restrict__ Kt, float* __restrict__ Vt) {
  __shared__ float xl[8][512];     // 16 KB
  __shared__ float qkvl[8][1024];  // 32 KB
  const int tid = threadIdx.x;
  const int row0 = blockIdx.x * 8;

  for (int l = tid; l < 8 * 512; l += 256) {
    int rr = l >> 9, i = l & 511;
    xl[rr][i] = x[(size_t)(row0 + rr) * 512 + i];
  }
  __syncthreads();

  float acc[4][8];
#pragma unroll
  for (int k = 0; k < 4; ++k)
#pragma unroll
    for (int rr = 0; rr < 8; ++rr) acc[k][rr] = 0.f;

  for (int i = 0; i < 512; ++i) {
    float w0 = Wq[i * 512 + tid];
    float w1 = Wq[i * 512 + tid + 256];
    float w2 = Wk[i * 256 + tid];
    float w3 = Wv[i * 256 + tid];
#pragma unroll
    for (int rr = 0; rr < 8; ++rr) {
      float xv = xl[rr][i];
      acc[0][rr] += xv * w0;
      acc[1][rr] += xv * w1;
      acc[2][rr] += xv * w2;
      acc[3][rr] += xv * w3;
    }
  }

#pragma unroll
  for (int rr = 0; rr < 8; ++rr) {
    qkvl[rr][tid] = acc[0][rr];
    qkvl[rr][tid + 256] = acc[1][rr];
    qkvl[rr][tid + 512] = acc[2][rr];
    qkvl[rr][tid + 768] = acc[3][rr];
  }
  __syncthreads();

  // RoPE: out[d<32] = t1*c + t2*s ; out[d>=32] = -t1*s + t2*c
  for (int l = tid; l < 8 * 1024; l += 256) {
    int rr = l >> 10, o = l & 1023;
    int row = row0 + rr;
    int b = row >> 10, t = row & 1023;
    if (o < 512) {
      int h = o >> 6, d = o & 63, dd = d & 31;
      float c = cosb[t * 32 + dd], s = sinb[t * 32 + dd];
      float v1 = qkvl[rr][h * 64 + dd];
      float v2 = qkvl[rr][h * 64 + dd + 32];
      float val = (d < 32) ? (v1 * c + v2 * s) : (v2 * c - v1 * s);
      Q[((size_t)(b * HH + h) * TT + t) * 64 + d] = val;
    } else if (o < 768) {
      int h = (o - 512) >> 6, d = o & 63, dd = d & 31;
      float c = cosb[t * 32 + dd], s = sinb[t * 32 + dd];
      float v1 = qkvl[rr][512 + h * 64 + dd];
      float v2 = qkvl[rr][512 + h * 64 + dd + 32];
      float val = (d < 32) ? (v1 * c + v2 * s) : (v2 * c - v1 * s);
      Kt[((size_t)(b * KVHN + h) * TT + t) * 64 + d] = val;
    } else {
      int o2 = o - 768;
      int h = o2 >> 6, d = o2 & 63;
      Vt[((size_t)(b * KVHN + h) * TT + t) * 64 + d] = qkvl[rr][768 + h * 64 + d];
    }
  }
}

// ---------------------------------------------------------------------------
// K2: causal logits + softmax -> A (G,T,T) f32, chunk-local system index.
// Grid: G*T blocks, 256 threads; one block per attention row.
// ---------------------------------------------------------------------------
__global__ __launch_bounds__(256) void attn_softmax_kernel(
    const float* __restrict__ Q, const float* __restrict__ Kt,
    float* __restrict__ A, int sys0) {
  const int tid = threadIdx.x;
  const int sl = blockIdx.x;  // ls*T + i
  const int i = sl & 1023;
  const int ls = sl >> 10;
  const int sys = sys0 + ls;  // global system = b*H + h
  const int b = sys >> 3, h = sys & 7, kvh = h >> 1;

  __shared__ float qrow[64];
  __shared__ float red[4];
  if (tid < 64) qrow[tid] = Q[((size_t)sys * TT + i) * 64 + tid];
  __syncthreads();

  const float* Kb = Kt + ((size_t)(b * KVHN + kvh) * TT) * 64;
  float lg[4];
#pragma unroll
  for (int jj = 0; jj < 4; ++jj) {
    int j = tid + jj * 256;
    lg[jj] = -INFINITY;
    if (j <= i) {
      const float* kr = Kb + (size_t)j * 64;
      float dot = 0.f;
#pragma unroll
      for (int d = 0; d < 64; d += 4) {
        float4 k4 = *reinterpret_cast<const float4*>(kr + d);
        dot += qrow[d] * k4.x + qrow[d + 1] * k4.y + qrow[d + 2] * k4.z +
               qrow[d + 3] * k4.w;
      }
      lg[jj] = dot * 0.125f;
    }
  }

  float m = fmaxf(fmaxf(lg[0], lg[1]), fmaxf(lg[2], lg[3]));
#pragma unroll
  for (int off = 32; off; off >>= 1) m = fmaxf(m, __shfl_xor(m, off));
  if ((tid & 63) == 0) red[tid >> 6] = m;
  __syncthreads();
  m = fmaxf(fmaxf(red[0], red[1]), fmaxf(red[2], red[3]));
  __syncthreads();

  float p[4];
  float sum = 0.f;
#pragma unroll
  for (int jj = 0; jj < 4; ++jj) {
    int j = tid + jj * 256;
    p[jj] = (j <= i) ? expf(lg[jj] - m) : 0.f;
    sum += p[jj];
  }
#pragma unroll
  for (int off = 32; off; off >>= 1) sum += __shfl_xor(sum, off);
  if ((tid & 63) == 0) red[tid >> 6] = sum;
  __syncthreads();
  sum = red[0] + red[1] + red[2] + red[3];
  float inv = 1.0f / sum;

  float* Ar = A + (size_t)sl * 1024;
#pragma unroll
  for (int jj = 0; jj < 4; ++jj) {
    int j = tid + jj * 256;
    if (j <= i) Ar[j] = p[jj] * inv;
  }
}

// ---------------------------------------------------------------------------
// K3: blocked forward substitution for (I + A) y = v, one 64-row block step.
// f64 accumulation. Grid: (8 colgroups, G systems), 256 threads.
// ---------------------------------------------------------------------------
__global__ __launch_bounds__(256) void solve_step_kernel(
    const float* __restrict__ A, const float* __restrict__ Vt,
    float* __restrict__ Y, int step, int sys0) {
  const int tid = threadIdx.x;
  const int cg = blockIdx.x;   // 0..7
  const int ls = blockIdx.y;   // 0..G-1 (chunk-local)
  const int sys = sys0 + ls;   // global b*H + h
  const int b = sys >> 3, h = sys & 7, kvh = h >> 1;
  const int c0 = cg * 8;
  const int r = tid & 63, c2 = tid >> 6;

  const float* Ab = A + (size_t)ls * TT * TT;
  const float* Vb = Vt + ((size_t)(b * KVHN + kvh) * TT) * 64;
  float* Yb = Y + (size_t)sys * TT * 64;

  __shared__ float At[64][65];
  __shared__ float Yt[64][8];
  __shared__ double u[64][9];

  const int rg0 = step * 64;
  double acc0 = 0.0, acc1 = 0.0;

  for (int jt = 0; jt < step; ++jt) {
    for (int l = tid; l < 4096; l += 256) {
      int rr = l >> 6, jj = l & 63;
      At[rr][jj] = Ab[(size_t)(rg0 + rr) * TT + jt * 64 + jj];
    }
    for (int l = tid; l < 512; l += 256) {
      int jj = l >> 3, c = l & 7;
      Yt[jj][c] = Yb[(size_t)(jt * 64 + jj) * 64 + c0 + c];
    }
    __syncthreads();
#pragma unroll
    for (int jj = 0; jj < 64; ++jj) {
      double a = (double)At[r][jj];
      acc0 += a * (double)Yt[jj][c2 * 2];
      acc1 += a * (double)Yt[jj][c2 * 2 + 1];
    }
    __syncthreads();
  }

  // diagonal tile
  for (int l = tid; l < 4096; l += 256) {
    int rr = l >> 6, jj = l & 63;
    At[rr][jj] = Ab[(size_t)(rg0 + rr) * TT + rg0 + jj];
  }
  u[r][c2 * 2] = (double)Vb[(size_t)(rg0 + r) * 64 + c0 + c2 * 2] - acc0;
  u[r][c2 * 2 + 1] = (double)Vb[(size_t)(rg0 + r) * 64 + c0 + c2 * 2 + 1] - acc1;
  __syncthreads();

  for (int r2 = 0; r2 < 63; ++r2) {
    if (r > r2) {
      double dinv = 1.0 / (1.0 + (double)At[r2][r2]);
      double y0 = u[r2][c2 * 2] * dinv;
      double y1 = u[r2][c2 * 2 + 1] * dinv;
      double a = (double)At[r][r2];
      u[r][c2 * 2] -= a * y0;
      u[r][c2 * 2 + 1] -= a * y1;
    }
    __syncthreads();
  }

  double dinv = 1.0 / (1.0 + (double)At[r][r]);
  Yb[(size_t)(rg0 + r) * 64 + c0 + c2 * 2] = (float)(u[r][c2 * 2] * dinv);
  Yb[(size_t)(rg0 + r) * 64 + c0 + c2 * 2 + 1] =
      (float)(u[r][c2 * 2 + 1] * dinv);
}

// ---------------------------------------------------------------------------
// K4: out = x + (y as (B,T,C)) @ Wo   — OUTPUT IS FLOAT32 (reference dtype).
// ---------------------------------------------------------------------------
__global__ __launch_bounds__(256) void out_proj_kernel(
    const float* __restrict__ Y, const float* __restrict__ x,
    const float* __restrict__ Wo, float* __restrict__ out) {
  __shared__ float yl[8][512];
  const int tid = threadIdx.x;
  const int row0 = blockIdx.x * 8;

  for (int l = tid; l < 4096; l += 256) {
    int rr = l >> 9, o = l & 511;
    int row = row0 + rr;
    int b = row >> 10, t = row & 1023;
    int h = o >> 6, d = o & 63;
    yl[rr][o] = Y[((size_t)(b * HH + h) * TT + t) * 64 + d];
  }
  __syncthreads();

  float acc[2][8];
#pragma unroll
  for (int k = 0; k < 2; ++k)
#pragma unroll
    for (int rr = 0; rr < 8; ++rr) acc[k][rr] = 0.f;

  for (int i = 0; i < 512; ++i) {
    float w0 = Wo[i * 512 + tid];
    float w1 = Wo[i * 512 + tid + 256];
#pragma unroll
    for (int rr = 0; rr < 8; ++rr) {
      float yv = yl[rr][i];
      acc[0][rr] += yv * w0;
      acc[1][rr] += yv * w1;
    }
  }

#pragma unroll
  for (int rr = 0; rr < 8; ++rr) {
    size_t row = (size_t)(row0 + rr);
    out[row * 512 + tid] = x[row * 512 + tid] + acc[0][rr];
    out[row * 512 + tid + 256] = x[row * 512 + tid + 256] + acc[1][rr];
  }
}

// ---------------------------------------------------------------------------
extern "C" void kernel_launch(void* const* d_in, const int* in_sizes, int n_in,
                              void* d_out, int out_size, void* d_ws,
                              size_t ws_size, hipStream_t stream) {
  (void)in_sizes;
  (void)n_in;
  (void)out_size;
  const float* x = (const float*)d_in[0];
  const float* cosb = (const float*)d_in[1];
  const float* sinb = (const float*)d_in[2];
  const float* Wq = (const float*)d_in[3];
  const float* Wk = (const float*)d_in[4];
  const float* Wv = (const float*)d_in[5];
  const float* Wo = (const float*)d_in[6];
  float* out = (float*)d_out;

  float* ws = (float*)d_ws;
  float* Q = ws;                    // 16*1024*64 = 1,048,576 f
  float* Kt = Q + (size_t)1048576;  // 8*1024*64  =   524,288 f
  float* Vt = Kt + (size_t)524288;  //               524,288 f
  float* Y = Vt + (size_t)524288;   //             1,048,576 f
  float* A = Y + (size_t)1048576;   // G*1024*1024 f (A goes LAST — sized to ws)

  // ws-adaptive chunk size over the 16 (b,h) systems
  const size_t baseF = 1048576 + 524288 + 524288 + 1048576;  // 3,145,728
  const size_t wsF = ws_size / 4;
  int G = 16;
  while (G > 1 && baseF + (size_t)G * 1048576ull > wsF) G >>= 1;

  qkv_rope_kernel<<<256, 256, 0, stream>>>(x, cosb, sinb, Wq, Wk, Wv, Q, Kt,
                                           Vt);
  for (int sys0 = 0; sys0 < 16; sys0 += G) {
    attn_softmax_kernel<<<G * 1024, 256, 0, stream>>>(Q, Kt, A, sys0);
    for (int step = 0; step < 16; ++step) {
      solve_step_kernel<<<dim3(8, G), 256, 0, stream>>>(A, Vt, Y, step, sys0);
    }
  }
  out_proj_kernel<<<256, 256, 0, stream>>>(Y, x, Wo, out);
}

// Round 6
// 592.883 us; speedup vs baseline: 2.5089x; 2.5089x over previous
//
#include <hip/hip_runtime.h>
#include <cmath>

// Problem constants
#define TT 1024
#define HH 8
#define KVHN 4

// ---------------------------------------------------------------------------
// K1: fused QKV projection + RoPE (unchanged from passing round).
// Grid: 256 blocks, 256 threads.
// ---------------------------------------------------------------------------
__global__ __launch_bounds__(256) void qkv_rope_kernel(
    const float* __restrict__ x, const float* __restrict__ cosb,
    const float* __restrict__ sinb, const float* __restrict__ Wq,
    const float* __restrict__ Wk, const float* __restrict__ Wv,
    float* __restrict__ Q, float* __restrict__ Kt, float* __restrict__ Vt) {
  __shared__ float xl[8][512];
  __shared__ float qkvl[8][1024];
  const int tid = threadIdx.x;
  const int row0 = blockIdx.x * 8;

  for (int l = tid; l < 8 * 512; l += 256) {
    int rr = l >> 9, i = l & 511;
    xl[rr][i] = x[(size_t)(row0 + rr) * 512 + i];
  }
  __syncthreads();

  float acc[4][8];
#pragma unroll
  for (int k = 0; k < 4; ++k)
#pragma unroll
    for (int rr = 0; rr < 8; ++rr) acc[k][rr] = 0.f;

  for (int i = 0; i < 512; ++i) {
    float w0 = Wq[i * 512 + tid];
    float w1 = Wq[i * 512 + tid + 256];
    float w2 = Wk[i * 256 + tid];
    float w3 = Wv[i * 256 + tid];
#pragma unroll
    for (int rr = 0; rr < 8; ++rr) {
      float xv = xl[rr][i];
      acc[0][rr] += xv * w0;
      acc[1][rr] += xv * w1;
      acc[2][rr] += xv * w2;
      acc[3][rr] += xv * w3;
    }
  }

#pragma unroll
  for (int rr = 0; rr < 8; ++rr) {
    qkvl[rr][tid] = acc[0][rr];
    qkvl[rr][tid + 256] = acc[1][rr];
    qkvl[rr][tid + 512] = acc[2][rr];
    qkvl[rr][tid + 768] = acc[3][rr];
  }
  __syncthreads();

  for (int l = tid; l < 8 * 1024; l += 256) {
    int rr = l >> 10, o = l & 1023;
    int row = row0 + rr;
    int b = row >> 10, t = row & 1023;
    if (o < 512) {
      int h = o >> 6, d = o & 63, dd = d & 31;
      float c = cosb[t * 32 + dd], s = sinb[t * 32 + dd];
      float v1 = qkvl[rr][h * 64 + dd];
      float v2 = qkvl[rr][h * 64 + dd + 32];
      float val = (d < 32) ? (v1 * c + v2 * s) : (v2 * c - v1 * s);
      Q[((size_t)(b * HH + h) * TT + t) * 64 + d] = val;
    } else if (o < 768) {
      int h = (o - 512) >> 6, d = o & 63, dd = d & 31;
      float c = cosb[t * 32 + dd], s = sinb[t * 32 + dd];
      float v1 = qkvl[rr][512 + h * 64 + dd];
      float v2 = qkvl[rr][512 + h * 64 + dd + 32];
      float val = (d < 32) ? (v1 * c + v2 * s) : (v2 * c - v1 * s);
      Kt[((size_t)(b * KVHN + h) * TT + t) * 64 + d] = val;
    } else {
      int o2 = o - 768;
      int h = o2 >> 6, d = o2 & 63;
      Vt[((size_t)(b * KVHN + h) * TT + t) * 64 + d] = qkvl[rr][768 + h * 64 + d];
    }
  }
}

// invs embed helper: invs values live in A[sys=15], rows 0..31, cols 512..1023
// (tiles (it=0, jt>=8) of system 15 -- never written or read otherwise).
__device__ __forceinline__ size_t invs_slot(int idx) {
  return (size_t)((idx >> 9) << 10) + 512 + (idx & 511);
}

// ---------------------------------------------------------------------------
// K2: tiled causal logits + exp (UNNORMALIZED) -> A; per-row 1/sum -> invs.
// Grid: (16 i-tiles, 16 systems), 256 threads. Block = 64 q-rows.
// Each thread owns a 4x4 micro-tile; K-tile staged in LDS, reused by 64 rows.
// No max-subtraction: logits are O(few), exp is safe in f32.
// ---------------------------------------------------------------------------
__global__ __launch_bounds__(256) void logits_exp_kernel(
    const float* __restrict__ Q, const float* __restrict__ Kt,
    float* __restrict__ A, float* __restrict__ invs) {
  const int it = blockIdx.x, sys = blockIdx.y;
  const int b = sys >> 3, kvh = (sys & 7) >> 1;
  const int tid = threadIdx.x;
  const int ti = tid >> 4, tj = tid & 15;

  __shared__ float Qt[64][68];   // row stride 272 B (16B-divisible)
  __shared__ float KtS[64][68];
  __shared__ float red[64][17];

  const float* Qb = Q + ((size_t)sys * TT + it * 64) * 64;
  const float* Kb = Kt + ((size_t)(b * KVHN + kvh) * TT) * 64;
  float* Aout = A + ((size_t)sys << 20);

  // 64x64 tile = 1024 float4s; f = m*256 + tid; rr = f/16, dc = (f%16)*4
#pragma unroll
  for (int m = 0; m < 4; ++m) {
    int f = m * 256 + tid;
    int rr = f >> 4, dc = (f & 15) * 4;
    float4 v = *reinterpret_cast<const float4*>(Qb + (size_t)rr * 64 + dc);
    *reinterpret_cast<float4*>(&Qt[rr][dc]) = v;
  }

  float rs[4] = {0.f, 0.f, 0.f, 0.f};

  for (int jt = 0; jt <= it; ++jt) {
    __syncthreads();  // previous KtS readers done (also publishes Qt on jt=0)
#pragma unroll
    for (int m = 0; m < 4; ++m) {
      int f = m * 256 + tid;
      int rr = f >> 4, dc = (f & 15) * 4;
      float4 v = *reinterpret_cast<const float4*>(
          Kb + (size_t)(jt * 64 + rr) * 64 + dc);
      *reinterpret_cast<float4*>(&KtS[rr][dc]) = v;
    }
    __syncthreads();

    float acc[4][4] = {};
    for (int d = 0; d < 64; d += 4) {
      float4 qv[4], kv[4];
#pragma unroll
      for (int i2 = 0; i2 < 4; ++i2)
        qv[i2] = *reinterpret_cast<const float4*>(&Qt[4 * ti + i2][d]);
#pragma unroll
      for (int j2 = 0; j2 < 4; ++j2)
        kv[j2] = *reinterpret_cast<const float4*>(&KtS[4 * tj + j2][d]);
#pragma unroll
      for (int i2 = 0; i2 < 4; ++i2)
#pragma unroll
        for (int j2 = 0; j2 < 4; ++j2)
          acc[i2][j2] += qv[i2].x * kv[j2].x + qv[i2].y * kv[j2].y +
                         qv[i2].z * kv[j2].z + qv[i2].w * kv[j2].w;
    }

    int Jb = jt * 64 + 4 * tj;
#pragma unroll
    for (int ir = 0; ir < 4; ++ir) {
      int I = it * 64 + 4 * ti + ir;
      float4 ev;
      float e;
      e = (Jb + 0 <= I) ? __expf(acc[ir][0] * 0.125f) : 0.f; rs[ir] += e; ev.x = e;
      e = (Jb + 1 <= I) ? __expf(acc[ir][1] * 0.125f) : 0.f; rs[ir] += e; ev.y = e;
      e = (Jb + 2 <= I) ? __expf(acc[ir][2] * 0.125f) : 0.f; rs[ir] += e; ev.z = e;
      e = (Jb + 3 <= I) ? __expf(acc[ir][3] * 0.125f) : 0.f; rs[ir] += e; ev.w = e;
      *reinterpret_cast<float4*>(Aout + (size_t)I * 1024 + Jb) = ev;
    }
  }

  __syncthreads();
#pragma unroll
  for (int ir = 0; ir < 4; ++ir) red[4 * ti + ir][tj] = rs[ir];
  __syncthreads();
  if (tid < 64) {
    float s = 0.f;
#pragma unroll
    for (int t2 = 0; t2 < 16; ++t2) s += red[tid][t2];
    int idx = sys * 1024 + it * 64 + tid;
    invs[invs_slot(idx)] = 1.0f / s;
  }
}

// ---------------------------------------------------------------------------
// K3a: invert each normalized diagonal block (I + S*L_kk) IN PLACE over A.
// Grid: (16 k, 16 sys), 256 threads. Upper triangle of W stays exactly 0.
// ---------------------------------------------------------------------------
__global__ __launch_bounds__(256) void diaginv_kernel(
    float* __restrict__ A, const float* __restrict__ invs) {
  const int k = blockIdx.x, sys = blockIdx.y;
  const int tid = threadIdx.x;
  const int r = tid & 63, cq = tid >> 6;  // thread: row r, cols cq*16..+15

  float* Ab = A + ((size_t)sys << 20) + (size_t)(k * 64) * 1024 + k * 64;

  __shared__ float Lt[64][65];
  __shared__ float W[64][65];
  __shared__ float sv[64];

#pragma unroll
  for (int m = 0; m < 4; ++m) {
    int f = m * 256 + tid;
    int rr = f >> 4, jc = (f & 15) * 4;
    float4 v = *reinterpret_cast<const float4*>(Ab + (size_t)rr * 1024 + jc);
    Lt[rr][jc] = v.x; Lt[rr][jc + 1] = v.y; Lt[rr][jc + 2] = v.z; Lt[rr][jc + 3] = v.w;
  }
  if (tid < 64) {
    int idx = sys * 1024 + k * 64 + tid;
    sv[tid] = invs[invs_slot(idx)];
  }
#pragma unroll
  for (int c = 0; c < 16; ++c) W[r][cq * 16 + c] = (r == cq * 16 + c) ? 1.f : 0.f;
  __syncthreads();

  for (int r2 = 0; r2 < 64; ++r2) {
    float dinv = 1.0f / (1.0f + sv[r2] * Lt[r2][r2]);
    if (r == r2) {
#pragma unroll
      for (int c = 0; c < 16; ++c) W[r2][cq * 16 + c] *= dinv;
    }
    __syncthreads();
    if (r > r2) {
      float f = sv[r] * Lt[r][r2];
#pragma unroll
      for (int c = 0; c < 16; ++c) W[r][cq * 16 + c] -= f * W[r2][cq * 16 + c];
    }
    __syncthreads();
  }

  for (int m = 0; m < 16; ++m) {
    int idx = m * 256 + tid;
    int rr = idx >> 6, c = idx & 63;
    Ab[(size_t)rr * 1024 + c] = W[rr][c];
  }
}

// ---------------------------------------------------------------------------
// K3b: full forward solve, one block per (colgroup of 8, sys). 128 blocks.
// Y-strip (8 cols x 1024 rows) lives in LDS; 16 steps internal to the block.
// Diagonal apply = matmul with pre-inverted tile (no serial substitution).
// ---------------------------------------------------------------------------
__global__ __launch_bounds__(256) void solve_strip_kernel(
    const float* __restrict__ A, const float* __restrict__ invs,
    const float* __restrict__ Vt, float* __restrict__ Y) {
  const int cg = blockIdx.x, sys = blockIdx.y;
  const int b = sys >> 3, kvh = (sys & 7) >> 1;
  const int tid = threadIdx.x;
  const int r = tid & 63, w = tid >> 6;  // row r; wave w -> cols c0+w, c0+w+4
  const int c0 = cg * 8;

  const float* Ab = A + ((size_t)sys << 20);
  const float* Vb = Vt + ((size_t)(b * KVHN + kvh) * TT) * 64;
  float* Yb = Y + (size_t)sys * TT * 64;

  __shared__ float Yt[8][1024];  // [col][row] strip
  __shared__ float At[64][65];
  __shared__ float uS[64][9];

  for (int k = 0; k < 16; ++k) {
    const int gr = k * 64 + r;
    const int iidx = sys * 1024 + gr;
    const float sinv = invs[invs_slot(iidx)];
    float u0 = Vb[(size_t)gr * 64 + c0 + w];
    float u1 = Vb[(size_t)gr * 64 + c0 + w + 4];
    float accA = 0.f, accB = 0.f;

    for (int jt = 0; jt < k; ++jt) {
#pragma unroll
      for (int m = 0; m < 4; ++m) {
        int f = m * 256 + tid;
        int rr = f >> 4, jc = (f & 15) * 4;
        float4 v = *reinterpret_cast<const float4*>(
            Ab + (size_t)(k * 64 + rr) * 1024 + jt * 64 + jc);
        At[rr][jc] = v.x; At[rr][jc + 1] = v.y; At[rr][jc + 2] = v.z; At[rr][jc + 3] = v.w;
      }
      __syncthreads();
      const float* Y0 = &Yt[w][jt * 64];
      const float* Y1 = &Yt[w + 4][jt * 64];
#pragma unroll
      for (int jj = 0; jj < 64; ++jj) {
        float a = At[r][jj];
        accA += a * Y0[jj];
        accB += a * Y1[jj];
      }
      __syncthreads();
    }

    u0 -= sinv * accA;
    u1 -= sinv * accB;
    uS[r][w] = u0;
    uS[r][w + 4] = u1;

    // stage inverted diagonal tile M_k into At
#pragma unroll
    for (int m = 0; m < 4; ++m) {
      int f = m * 256 + tid;
      int rr = f >> 4, jc = (f & 15) * 4;
      float4 v = *reinterpret_cast<const float4*>(
          Ab + (size_t)(k * 64 + rr) * 1024 + k * 64 + jc);
      At[rr][jc] = v.x; At[rr][jc + 1] = v.y; At[rr][jc + 2] = v.z; At[rr][jc + 3] = v.w;
    }
    __syncthreads();

    float y0 = 0.f, y1 = 0.f;
#pragma unroll
    for (int jj = 0; jj < 64; ++jj) {
      float mm = At[r][jj];
      y0 += mm * uS[jj][w];
      y1 += mm * uS[jj][w + 4];
    }
    Yt[w][k * 64 + r] = y0;
    Yt[w + 4][k * 64 + r] = y1;
    Yb[(size_t)gr * 64 + c0 + w] = y0;
    Yb[(size_t)gr * 64 + c0 + w + 4] = y1;
    __syncthreads();
  }
}

// ---------------------------------------------------------------------------
// K4: out = x + (y as (B,T,C)) @ Wo  (f32 output) — unchanged.
// ---------------------------------------------------------------------------
__global__ __launch_bounds__(256) void out_proj_kernel(
    const float* __restrict__ Y, const float* __restrict__ x,
    const float* __restrict__ Wo, float* __restrict__ out) {
  __shared__ float yl[8][512];
  const int tid = threadIdx.x;
  const int row0 = blockIdx.x * 8;

  for (int l = tid; l < 4096; l += 256) {
    int rr = l >> 9, o = l & 511;
    int row = row0 + rr;
    int b = row >> 10, t = row & 1023;
    int h = o >> 6, d = o & 63;
    yl[rr][o] = Y[((size_t)(b * HH + h) * TT + t) * 64 + d];
  }
  __syncthreads();

  float acc[2][8];
#pragma unroll
  for (int k = 0; k < 2; ++k)
#pragma unroll
    for (int rr = 0; rr < 8; ++rr) acc[k][rr] = 0.f;

  for (int i = 0; i < 512; ++i) {
    float w0 = Wo[i * 512 + tid];
    float w1 = Wo[i * 512 + tid + 256];
#pragma unroll
    for (int rr = 0; rr < 8; ++rr) {
      float yv = yl[rr][i];
      acc[0][rr] += yv * w0;
      acc[1][rr] += yv * w1;
    }
  }

#pragma unroll
  for (int rr = 0; rr < 8; ++rr) {
    size_t row = (size_t)(row0 + rr);
    out[row * 512 + tid] = x[row * 512 + tid] + acc[0][rr];
    out[row * 512 + tid + 256] = x[row * 512 + tid + 256] + acc[1][rr];
  }
}

// ---------------------------------------------------------------------------
extern "C" void kernel_launch(void* const* d_in, const int* in_sizes, int n_in,
                              void* d_out, int out_size, void* d_ws,
                              size_t ws_size, hipStream_t stream) {
  (void)in_sizes; (void)n_in; (void)out_size; (void)ws_size;
  const float* x = (const float*)d_in[0];
  const float* cosb = (const float*)d_in[1];
  const float* sinb = (const float*)d_in[2];
  const float* Wq = (const float*)d_in[3];
  const float* Wk = (const float*)d_in[4];
  const float* Wv = (const float*)d_in[5];
  const float* Wo = (const float*)d_in[6];
  float* out = (float*)d_out;

  float* ws = (float*)d_ws;
  float* Q = ws;                    // 1,048,576 f
  float* Kt = Q + (size_t)1048576;  //   524,288 f
  float* Vt = Kt + (size_t)524288;  //   524,288 f
  float* Y = Vt + (size_t)524288;   // 1,048,576 f
  float* A = Y + (size_t)1048576;   // 16,777,216 f  (total 76 MiB, proven fit)
  float* invs = A + (size_t)15 * 1048576;  // embedded in A[sys=15] upper region

  qkv_rope_kernel<<<256, 256, 0, stream>>>(x, cosb, sinb, Wq, Wk, Wv, Q, Kt, Vt);
  logits_exp_kernel<<<dim3(16, 16), 256, 0, stream>>>(Q, Kt, A, invs);
  diaginv_kernel<<<dim3(16, 16), 256, 0, stream>>>(A, invs);
  solve_strip_kernel<<<dim3(8, 16), 256, 0, stream>>>(A, invs, Vt, Y);
  out_proj_kernel<<<256, 256, 0, stream>>>(Y, x, Wo, out);
}

// Round 7
// 402.383 us; speedup vs baseline: 3.6967x; 1.4734x over previous
//
#include <hip/hip_runtime.h>
#include <cmath>

// Problem constants
#define TT 1024
#define HH 8
#define KVHN 4

typedef unsigned short u16;

// bf16 helpers (raw u16 storage; bf16->f32 = shift, f32->bf16 = RNE round)
__device__ __forceinline__ float bflo(unsigned u) { return __uint_as_float(u << 16); }
__device__ __forceinline__ float bfhi(unsigned u) { return __uint_as_float(u & 0xffff0000u); }
__device__ __forceinline__ u16 bfr(float f) {
  unsigned u = __float_as_uint(f);
  return (u16)((u + 0x7fffu + ((u >> 16) & 1u)) >> 16);
}

// ---------------------------------------------------------------------------
// K1: fused QKV projection + RoPE (unchanged).
// ---------------------------------------------------------------------------
__global__ __launch_bounds__(256) void qkv_rope_kernel(
    const float* __restrict__ x, const float* __restrict__ cosb,
    const float* __restrict__ sinb, const float* __restrict__ Wq,
    const float* __restrict__ Wk, const float* __restrict__ Wv,
    float* __restrict__ Q, float* __restrict__ Kt, float* __restrict__ Vt) {
  __shared__ float xl[8][512];
  __shared__ float qkvl[8][1024];
  const int tid = threadIdx.x;
  const int row0 = blockIdx.x * 8;

  for (int l = tid; l < 8 * 512; l += 256) {
    int rr = l >> 9, i = l & 511;
    xl[rr][i] = x[(size_t)(row0 + rr) * 512 + i];
  }
  __syncthreads();

  float acc[4][8];
#pragma unroll
  for (int k = 0; k < 4; ++k)
#pragma unroll
    for (int rr = 0; rr < 8; ++rr) acc[k][rr] = 0.f;

  for (int i = 0; i < 512; ++i) {
    float w0 = Wq[i * 512 + tid];
    float w1 = Wq[i * 512 + tid + 256];
    float w2 = Wk[i * 256 + tid];
    float w3 = Wv[i * 256 + tid];
#pragma unroll
    for (int rr = 0; rr < 8; ++rr) {
      float xv = xl[rr][i];
      acc[0][rr] += xv * w0;
      acc[1][rr] += xv * w1;
      acc[2][rr] += xv * w2;
      acc[3][rr] += xv * w3;
    }
  }

#pragma unroll
  for (int rr = 0; rr < 8; ++rr) {
    qkvl[rr][tid] = acc[0][rr];
    qkvl[rr][tid + 256] = acc[1][rr];
    qkvl[rr][tid + 512] = acc[2][rr];
    qkvl[rr][tid + 768] = acc[3][rr];
  }
  __syncthreads();

  for (int l = tid; l < 8 * 1024; l += 256) {
    int rr = l >> 10, o = l & 1023;
    int row = row0 + rr;
    int b = row >> 10, t = row & 1023;
    if (o < 512) {
      int h = o >> 6, d = o & 63, dd = d & 31;
      float c = cosb[t * 32 + dd], s = sinb[t * 32 + dd];
      float v1 = qkvl[rr][h * 64 + dd];
      float v2 = qkvl[rr][h * 64 + dd + 32];
      float val = (d < 32) ? (v1 * c + v2 * s) : (v2 * c - v1 * s);
      Q[((size_t)(b * HH + h) * TT + t) * 64 + d] = val;
    } else if (o < 768) {
      int h = (o - 512) >> 6, d = o & 63, dd = d & 31;
      float c = cosb[t * 32 + dd], s = sinb[t * 32 + dd];
      float v1 = qkvl[rr][512 + h * 64 + dd];
      float v2 = qkvl[rr][512 + h * 64 + dd + 32];
      float val = (d < 32) ? (v1 * c + v2 * s) : (v2 * c - v1 * s);
      Kt[((size_t)(b * KVHN + h) * TT + t) * 64 + d] = val;
    } else {
      int o2 = o - 768;
      int h = o2 >> 6, d = o2 & 63;
      Vt[((size_t)(b * KVHN + h) * TT + t) * 64 + d] = qkvl[rr][768 + h * 64 + d];
    }
  }
}

// ---------------------------------------------------------------------------
// K2: tiled causal logits + exp (UNNORMALIZED) -> A (bf16); 1/rowsum -> invs.
// Grid: (16 i-tiles, 16 systems), 256 threads.
// ---------------------------------------------------------------------------
__global__ __launch_bounds__(256) void logits_exp_kernel(
    const float* __restrict__ Q, const float* __restrict__ Kt,
    u16* __restrict__ A, float* __restrict__ invs) {
  const int it = blockIdx.x, sys = blockIdx.y;
  const int b = sys >> 3, kvh = (sys & 7) >> 1;
  const int tid = threadIdx.x;
  const int ti = tid >> 4, tj = tid & 15;

  __shared__ float Qt[64][68];
  __shared__ float KtS[64][68];
  __shared__ float red[64][17];

  const float* Qb = Q + ((size_t)sys * TT + it * 64) * 64;
  const float* Kb = Kt + ((size_t)(b * KVHN + kvh) * TT) * 64;
  u16* Aout = A + ((size_t)sys << 20);

#pragma unroll
  for (int m = 0; m < 4; ++m) {
    int f = m * 256 + tid;
    int rr = f >> 4, dc = (f & 15) * 4;
    float4 v = *reinterpret_cast<const float4*>(Qb + (size_t)rr * 64 + dc);
    *reinterpret_cast<float4*>(&Qt[rr][dc]) = v;
  }

  float rs[4] = {0.f, 0.f, 0.f, 0.f};

  for (int jt = 0; jt <= it; ++jt) {
    __syncthreads();
#pragma unroll
    for (int m = 0; m < 4; ++m) {
      int f = m * 256 + tid;
      int rr = f >> 4, dc = (f & 15) * 4;
      float4 v = *reinterpret_cast<const float4*>(
          Kb + (size_t)(jt * 64 + rr) * 64 + dc);
      *reinterpret_cast<float4*>(&KtS[rr][dc]) = v;
    }
    __syncthreads();

    float acc[4][4] = {};
    for (int d = 0; d < 64; d += 4) {
      float4 qv[4], kv[4];
#pragma unroll
      for (int i2 = 0; i2 < 4; ++i2)
        qv[i2] = *reinterpret_cast<const float4*>(&Qt[4 * ti + i2][d]);
#pragma unroll
      for (int j2 = 0; j2 < 4; ++j2)
        kv[j2] = *reinterpret_cast<const float4*>(&KtS[4 * tj + j2][d]);
#pragma unroll
      for (int i2 = 0; i2 < 4; ++i2)
#pragma unroll
        for (int j2 = 0; j2 < 4; ++j2)
          acc[i2][j2] += qv[i2].x * kv[j2].x + qv[i2].y * kv[j2].y +
                         qv[i2].z * kv[j2].z + qv[i2].w * kv[j2].w;
    }

    int Jb = jt * 64 + 4 * tj;
#pragma unroll
    for (int ir = 0; ir < 4; ++ir) {
      int I = it * 64 + 4 * ti + ir;
      float4 ev;
      float e;
      e = (Jb + 0 <= I) ? __expf(acc[ir][0] * 0.125f) : 0.f; rs[ir] += e; ev.x = e;
      e = (Jb + 1 <= I) ? __expf(acc[ir][1] * 0.125f) : 0.f; rs[ir] += e; ev.y = e;
      e = (Jb + 2 <= I) ? __expf(acc[ir][2] * 0.125f) : 0.f; rs[ir] += e; ev.z = e;
      e = (Jb + 3 <= I) ? __expf(acc[ir][3] * 0.125f) : 0.f; rs[ir] += e; ev.w = e;
      uint2 pk;
      pk.x = (unsigned)bfr(ev.x) | ((unsigned)bfr(ev.y) << 16);
      pk.y = (unsigned)bfr(ev.z) | ((unsigned)bfr(ev.w) << 16);
      *reinterpret_cast<uint2*>(Aout + (size_t)I * 1024 + Jb) = pk;
    }
  }

  __syncthreads();
#pragma unroll
  for (int ir = 0; ir < 4; ++ir) red[4 * ti + ir][tj] = rs[ir];
  __syncthreads();
  if (tid < 64) {
    float s = 0.f;
#pragma unroll
    for (int t2 = 0; t2 < 16; ++t2) s += red[tid][t2];
    invs[sys * 1024 + it * 64 + tid] = 1.0f / s;
  }
}

// ---------------------------------------------------------------------------
// K3a: invert each (I + S*L_kk) diagonal block IN PLACE over bf16 A.
// Grid: (16 k, 16 sys), 256 threads.
// ---------------------------------------------------------------------------
__global__ __launch_bounds__(256) void diaginv_kernel(
    u16* __restrict__ A, const float* __restrict__ invs) {
  const int k = blockIdx.x, sys = blockIdx.y;
  const int tid = threadIdx.x;
  const int r = tid & 63, cq = tid >> 6;

  u16* Ab = A + ((size_t)sys << 20) + (size_t)(k * 64) * 1024 + k * 64;

  __shared__ float Lt[64][65];
  __shared__ float W[64][65];
  __shared__ float sv[64];

#pragma unroll
  for (int m = 0; m < 2; ++m) {
    int f = m * 256 + tid;
    int rr = f >> 3, ch = f & 7;
    uint4 v = *reinterpret_cast<const uint4*>(Ab + (size_t)rr * 1024 + ch * 8);
    float* dst = &Lt[rr][ch * 8];
    dst[0] = bflo(v.x); dst[1] = bfhi(v.x); dst[2] = bflo(v.y); dst[3] = bfhi(v.y);
    dst[4] = bflo(v.z); dst[5] = bfhi(v.z); dst[6] = bflo(v.w); dst[7] = bfhi(v.w);
  }
  if (tid < 64) sv[tid] = invs[sys * 1024 + k * 64 + tid];
#pragma unroll
  for (int c = 0; c < 16; ++c) W[r][cq * 16 + c] = (r == cq * 16 + c) ? 1.f : 0.f;
  __syncthreads();

  for (int r2 = 0; r2 < 64; ++r2) {
    float dinv = 1.0f / (1.0f + sv[r2] * Lt[r2][r2]);
    if (r == r2) {
#pragma unroll
      for (int c = 0; c < 16; ++c) W[r2][cq * 16 + c] *= dinv;
    }
    __syncthreads();
    if (r > r2) {
      float f = sv[r] * Lt[r][r2];
#pragma unroll
      for (int c = 0; c < 16; ++c) W[r][cq * 16 + c] -= f * W[r2][cq * 16 + c];
    }
    __syncthreads();
  }

  // writeback bf16, packed pairs (2048 u32 chunks, 8/thread)
#pragma unroll
  for (int m = 0; m < 8; ++m) {
    int f = m * 256 + tid;
    int rr = f >> 5, cp = (f & 31) * 2;
    unsigned pk = (unsigned)bfr(W[rr][cp]) | ((unsigned)bfr(W[rr][cp + 1]) << 16);
    *reinterpret_cast<unsigned*>(Ab + (size_t)rr * 1024 + cp) = pk;
  }
}

// ---------------------------------------------------------------------------
// K3b: forward solve, one block per (sys, colgroup-of-8). Grid dim3(16,8):
// linear id = cg*16+sys -> XCD = sys%8, so a sys's 8 blocks share one XCD L2.
// Swizzled f32 At double-buffer (reg-staged prefetch), wave-local row groups
// (tile crosses LDS once), broadcast float4 Y/u reads.
// ---------------------------------------------------------------------------
__global__ __launch_bounds__(256) void solve_strip_kernel(
    const u16* __restrict__ A, const float* __restrict__ invs,
    const float* __restrict__ Vt, float* __restrict__ Y) {
  const int sys = blockIdx.x, cg = blockIdx.y;
  const int b = sys >> 3, kvh = (sys & 7) >> 1;
  const int tid = threadIdx.x;
  const int w = tid >> 6, l = tid & 63;
  const int r = w * 16 + (l & 15);  // this thread's row in the 64-tile
  const int cw = l >> 4;            // 0..3 -> cols c0+cw, c0+cw+4
  const int c0 = cg * 8;

  const u16* Ab = A + ((size_t)sys << 20);
  const float* Vb = Vt + ((size_t)(b * KVHN + kvh) * TT) * 64;
  float* Yg = Y + (size_t)sys * TT * 64;

  __shared__ float At[2][64][64];  // XOR-swizzled on float4 slots
  __shared__ float Yt[8][1028];    // [local col][row]; pad: banks spread
  __shared__ float uT[8][68];

  const int rr0 = tid >> 3, ch = tid & 7;  // staging chunk: rows rr0, rr0+32

  uint4 vA, vB;
  auto issueL = [&](int kk, int jt) {
    const u16* base = Ab + (size_t)(kk * 64) * 1024 + jt * 64 + ch * 8;
    vA = *reinterpret_cast<const uint4*>(base + (size_t)rr0 * 1024);
    vB = *reinterpret_cast<const uint4*>(base + (size_t)(rr0 + 32) * 1024);
  };
  auto commitL = [&](int buf) {
    float4 lo, hi;
    int c4a = 2 * ch, c4b = 2 * ch + 1;
    lo.x = bflo(vA.x); lo.y = bfhi(vA.x); lo.z = bflo(vA.y); lo.w = bfhi(vA.y);
    hi.x = bflo(vA.z); hi.y = bfhi(vA.z); hi.z = bflo(vA.w); hi.w = bfhi(vA.w);
    *reinterpret_cast<float4*>(&At[buf][rr0][(c4a ^ (rr0 & 15)) << 2]) = lo;
    *reinterpret_cast<float4*>(&At[buf][rr0][(c4b ^ (rr0 & 15)) << 2]) = hi;
    lo.x = bflo(vB.x); lo.y = bfhi(vB.x); lo.z = bflo(vB.y); lo.w = bfhi(vB.y);
    hi.x = bflo(vB.z); hi.y = bfhi(vB.z); hi.z = bflo(vB.w); hi.w = bfhi(vB.w);
    int rb = rr0 + 32;
    *reinterpret_cast<float4*>(&At[buf][rb][(c4a ^ (rb & 15)) << 2]) = lo;
    *reinterpret_cast<float4*>(&At[buf][rb][(c4b ^ (rb & 15)) << 2]) = hi;
  };

  int cur = 0;
  issueL(0, 0);
  commitL(0);

  for (int k = 0; k < 16; ++k) {
    const float sinv = invs[sys * 1024 + k * 64 + r];
    const float v0 = Vb[(size_t)(k * 64 + r) * 64 + c0 + cw];
    const float v1 = Vb[(size_t)(k * 64 + r) * 64 + c0 + cw + 4];
    float accA = 0.f, accB = 0.f;

    for (int jt = 0; jt <= k; ++jt) {
      __syncthreads();  // At[cur] (and prev-k Yt) visible
      const bool last = (k == 15) && (jt == 15);
      if (!last) {
        const int nk = (jt == k) ? k + 1 : k;
        const int njt = (jt == k) ? 0 : jt + 1;
        issueL(nk, njt);
      }
      if (jt < k) {
        const float* Ya = &Yt[cw][jt * 64];
        const float* Yb2 = &Yt[cw + 4][jt * 64];
#pragma unroll
        for (int c4 = 0; c4 < 16; ++c4) {
          float4 a = *reinterpret_cast<const float4*>(
              &At[cur][r][(c4 ^ (r & 15)) << 2]);
          float4 ya = *reinterpret_cast<const float4*>(Ya + (c4 << 2));
          float4 yb = *reinterpret_cast<const float4*>(Yb2 + (c4 << 2));
          accA += a.x * ya.x + a.y * ya.y + a.z * ya.z + a.w * ya.w;
          accB += a.x * yb.x + a.y * yb.y + a.z * yb.z + a.w * yb.w;
        }
      } else {
        // diagonal: u = v - sinv*acc, then y = Minv * u
        float u0 = v0 - sinv * accA;
        float u1 = v1 - sinv * accB;
        uT[cw][r] = u0;
        uT[cw + 4][r] = u1;
        __syncthreads();
        float y0 = 0.f, y1 = 0.f;
#pragma unroll
        for (int c4 = 0; c4 < 16; ++c4) {
          float4 a = *reinterpret_cast<const float4*>(
              &At[cur][r][(c4 ^ (r & 15)) << 2]);
          float4 ua = *reinterpret_cast<const float4*>(&uT[cw][c4 << 2]);
          float4 ub = *reinterpret_cast<const float4*>(&uT[cw + 4][c4 << 2]);
          y0 += a.x * ua.x + a.y * ua.y + a.z * ua.z + a.w * ua.w;
          y1 += a.x * ub.x + a.y * ub.y + a.z * ub.z + a.w * ub.w;
        }
        Yt[cw][k * 64 + r] = y0;
        Yt[cw + 4][k * 64 + r] = y1;
        Yg[(size_t)(k * 64 + r) * 64 + c0 + cw] = y0;
        Yg[(size_t)(k * 64 + r) * 64 + c0 + cw + 4] = y1;
      }
      if (!last) {
        commitL(cur ^ 1);
        cur ^= 1;
      }
    }
  }
}

// ---------------------------------------------------------------------------
// K4: out = x + (y as (B,T,C)) @ Wo  (f32 output) — unchanged.
// ---------------------------------------------------------------------------
__global__ __launch_bounds__(256) void out_proj_kernel(
    const float* __restrict__ Y, const float* __restrict__ x,
    const float* __restrict__ Wo, float* __restrict__ out) {
  __shared__ float yl[8][512];
  const int tid = threadIdx.x;
  const int row0 = blockIdx.x * 8;

  for (int l = tid; l < 4096; l += 256) {
    int rr = l >> 9, o = l & 511;
    int row = row0 + rr;
    int b = row >> 10, t = row & 1023;
    int h = o >> 6, d = o & 63;
    yl[rr][o] = Y[((size_t)(b * HH + h) * TT + t) * 64 + d];
  }
  __syncthreads();

  float acc[2][8];
#pragma unroll
  for (int k = 0; k < 2; ++k)
#pragma unroll
    for (int rr = 0; rr < 8; ++rr) acc[k][rr] = 0.f;

  for (int i = 0; i < 512; ++i) {
    float w0 = Wo[i * 512 + tid];
    float w1 = Wo[i * 512 + tid + 256];
#pragma unroll
    for (int rr = 0; rr < 8; ++rr) {
      float yv = yl[rr][i];
      acc[0][rr] += yv * w0;
      acc[1][rr] += yv * w1;
    }
  }

#pragma unroll
  for (int rr = 0; rr < 8; ++rr) {
    size_t row = (size_t)(row0 + rr);
    out[row * 512 + tid] = x[row * 512 + tid] + acc[0][rr];
    out[row * 512 + tid + 256] = x[row * 512 + tid + 256] + acc[1][rr];
  }
}

// ---------------------------------------------------------------------------
extern "C" void kernel_launch(void* const* d_in, const int* in_sizes, int n_in,
                              void* d_out, int out_size, void* d_ws,
                              size_t ws_size, hipStream_t stream) {
  (void)in_sizes; (void)n_in; (void)out_size; (void)ws_size;
  const float* x = (const float*)d_in[0];
  const float* cosb = (const float*)d_in[1];
  const float* sinb = (const float*)d_in[2];
  const float* Wq = (const float*)d_in[3];
  const float* Wk = (const float*)d_in[4];
  const float* Wv = (const float*)d_in[5];
  const float* Wo = (const float*)d_in[6];
  float* out = (float*)d_out;

  float* ws = (float*)d_ws;
  float* Q = ws;                        // 1,048,576 f
  float* Kt = Q + (size_t)1048576;      //   524,288 f
  float* Vt = Kt + (size_t)524288;      //   524,288 f
  float* Yb = Vt + (size_t)524288;      // 1,048,576 f
  float* invs = Yb + (size_t)1048576;   //    16,384 f
  u16* A = (u16*)(invs + 16384);        // 16,777,216 bf16 = 32 MB; total ~46 MB

  qkv_rope_kernel<<<256, 256, 0, stream>>>(x, cosb, sinb, Wq, Wk, Wv, Q, Kt, Vt);
  logits_exp_kernel<<<dim3(16, 16), 256, 0, stream>>>(Q, Kt, A, invs);
  diaginv_kernel<<<dim3(16, 16), 256, 0, stream>>>(A, invs);
  solve_strip_kernel<<<dim3(16, 8), 256, 0, stream>>>(A, invs, Vt, Yb);
  out_proj_kernel<<<256, 256, 0, stream>>>(Yb, x, Wo, out);
}

// Round 8
// 328.162 us; speedup vs baseline: 4.5328x; 1.2262x over previous
//
#include <hip/hip_runtime.h>
#include <cmath>

#define TT 1024
#define HH 8
#define KVHN 4

typedef unsigned short u16;

__device__ __forceinline__ float bflo(unsigned u) { return __uint_as_float(u << 16); }
__device__ __forceinline__ float bfhi(unsigned u) { return __uint_as_float(u & 0xffff0000u); }
__device__ __forceinline__ u16 bfr(float f) {
  unsigned u = __float_as_uint(f);
  return (u16)((u + 0x7fffu + ((u >> 16) & 1u)) >> 16);
}

// ---------------------------------------------------------------------------
// K1: QKV projection as tiled GEMM + fused RoPE.
// Grid (32 row-tiles, 16 col-tiles), 256 threads. C = X(2048x512) @ W(512x1024)
// col-tiles: 0-7 -> Q head cy; 8-11 -> K head cy-8; 12-15 -> V head cy-12.
// ---------------------------------------------------------------------------
__global__ __launch_bounds__(256) void qkv_kernel(
    const float* __restrict__ x, const float* __restrict__ cosb,
    const float* __restrict__ sinb, const float* __restrict__ Wq,
    const float* __restrict__ Wk, const float* __restrict__ Wv,
    float* __restrict__ Q, float* __restrict__ Kt, float* __restrict__ Vt) {
  const int bx = blockIdx.x, cy = blockIdx.y;
  const int tid = threadIdx.x;
  const int ti = tid >> 4, tj = tid & 15;
  const int m0 = bx * 64;

  __shared__ float Xs[64][68];
  __shared__ float Ws[64][68];  // [k][col]

  const float* Wsel;
  int wstride, wc0;
  if (cy < 8) { Wsel = Wq; wstride = 512; wc0 = cy * 64; }
  else if (cy < 12) { Wsel = Wk; wstride = 256; wc0 = (cy - 8) * 64; }
  else { Wsel = Wv; wstride = 256; wc0 = (cy - 12) * 64; }

  float acc[4][4] = {};

  for (int k0 = 0; k0 < 512; k0 += 64) {
    __syncthreads();
#pragma unroll
    for (int m = 0; m < 4; ++m) {
      int f = m * 256 + tid;
      int rr = f >> 4, dc = (f & 15) * 4;
      *reinterpret_cast<float4*>(&Xs[rr][dc]) =
          *reinterpret_cast<const float4*>(x + (size_t)(m0 + rr) * 512 + k0 + dc);
    }
#pragma unroll
    for (int m = 0; m < 4; ++m) {
      int f = m * 256 + tid;
      int rr = f >> 4, dc = (f & 15) * 4;
      *reinterpret_cast<float4*>(&Ws[rr][dc]) =
          *reinterpret_cast<const float4*>(Wsel + (size_t)(k0 + rr) * wstride + wc0 + dc);
    }
    __syncthreads();

    for (int d = 0; d < 64; d += 4) {
      float4 wv[4];
#pragma unroll
      for (int dd = 0; dd < 4; ++dd)
        wv[dd] = *reinterpret_cast<const float4*>(&Ws[d + dd][4 * tj]);
#pragma unroll
      for (int i2 = 0; i2 < 4; ++i2) {
        float4 xv = *reinterpret_cast<const float4*>(&Xs[4 * ti + i2][d]);
        acc[i2][0] += xv.x * wv[0].x + xv.y * wv[1].x + xv.z * wv[2].x + xv.w * wv[3].x;
        acc[i2][1] += xv.x * wv[0].y + xv.y * wv[1].y + xv.z * wv[2].y + xv.w * wv[3].y;
        acc[i2][2] += xv.x * wv[0].z + xv.y * wv[1].z + xv.z * wv[2].z + xv.w * wv[3].z;
        acc[i2][3] += xv.x * wv[0].w + xv.y * wv[1].w + xv.z * wv[2].w + xv.w * wv[3].w;
      }
    }
  }

  // restage result into Xs, then RoPE (Q/K) or copy (V) and store.
  __syncthreads();
#pragma unroll
  for (int i2 = 0; i2 < 4; ++i2) {
    float4 v;
    v.x = acc[i2][0]; v.y = acc[i2][1]; v.z = acc[i2][2]; v.w = acc[i2][3];
    *reinterpret_cast<float4*>(&Xs[4 * ti + i2][4 * tj]) = v;
  }
  __syncthreads();

#pragma unroll
  for (int m = 0; m < 16; ++m) {
    int f = m * 256 + tid;
    int rr = f >> 6, d = f & 63;
    int row = m0 + rr, b = row >> 10, t = row & 1023;
    float val;
    if (cy < 12) {
      int dd = d & 31;
      float c = cosb[t * 32 + dd], s = sinb[t * 32 + dd];
      float v1 = Xs[rr][dd], v2 = Xs[rr][dd + 32];
      val = (d < 32) ? (v1 * c + v2 * s) : (v2 * c - v1 * s);
    } else {
      val = Xs[rr][d];
    }
    if (cy < 8)
      Q[((size_t)(b * HH + cy) * TT + t) * 64 + d] = val;
    else if (cy < 12)
      Kt[((size_t)(b * KVHN + cy - 8) * TT + t) * 64 + d] = val;
    else
      Vt[((size_t)(b * KVHN + cy - 12) * TT + t) * 64 + d] = val;
  }
}

// ---------------------------------------------------------------------------
// K2: tiled causal logits + exp (UNNORMALIZED) -> A (bf16); 1/rowsum -> invs.
// Grid: (16 i-tiles, 16 systems), 256 threads. (unchanged, proven)
// ---------------------------------------------------------------------------
__global__ __launch_bounds__(256) void logits_exp_kernel(
    const float* __restrict__ Q, const float* __restrict__ Kt,
    u16* __restrict__ A, float* __restrict__ invs) {
  const int it = blockIdx.x, sys = blockIdx.y;
  const int b = sys >> 3, kvh = (sys & 7) >> 1;
  const int tid = threadIdx.x;
  const int ti = tid >> 4, tj = tid & 15;

  __shared__ float Qt[64][68];
  __shared__ float KtS[64][68];
  __shared__ float red[64][17];

  const float* Qb = Q + ((size_t)sys * TT + it * 64) * 64;
  const float* Kb = Kt + ((size_t)(b * KVHN + kvh) * TT) * 64;
  u16* Aout = A + ((size_t)sys << 20);

#pragma unroll
  for (int m = 0; m < 4; ++m) {
    int f = m * 256 + tid;
    int rr = f >> 4, dc = (f & 15) * 4;
    float4 v = *reinterpret_cast<const float4*>(Qb + (size_t)rr * 64 + dc);
    *reinterpret_cast<float4*>(&Qt[rr][dc]) = v;
  }

  float rs[4] = {0.f, 0.f, 0.f, 0.f};

  for (int jt = 0; jt <= it; ++jt) {
    __syncthreads();
#pragma unroll
    for (int m = 0; m < 4; ++m) {
      int f = m * 256 + tid;
      int rr = f >> 4, dc = (f & 15) * 4;
      float4 v = *reinterpret_cast<const float4*>(
          Kb + (size_t)(jt * 64 + rr) * 64 + dc);
      *reinterpret_cast<float4*>(&KtS[rr][dc]) = v;
    }
    __syncthreads();

    float acc[4][4] = {};
    for (int d = 0; d < 64; d += 4) {
      float4 qv[4], kv[4];
#pragma unroll
      for (int i2 = 0; i2 < 4; ++i2)
        qv[i2] = *reinterpret_cast<const float4*>(&Qt[4 * ti + i2][d]);
#pragma unroll
      for (int j2 = 0; j2 < 4; ++j2)
        kv[j2] = *reinterpret_cast<const float4*>(&KtS[4 * tj + j2][d]);
#pragma unroll
      for (int i2 = 0; i2 < 4; ++i2)
#pragma unroll
        for (int j2 = 0; j2 < 4; ++j2)
          acc[i2][j2] += qv[i2].x * kv[j2].x + qv[i2].y * kv[j2].y +
                         qv[i2].z * kv[j2].z + qv[i2].w * kv[j2].w;
    }

    int Jb = jt * 64 + 4 * tj;
#pragma unroll
    for (int ir = 0; ir < 4; ++ir) {
      int I = it * 64 + 4 * ti + ir;
      float4 ev;
      float e;
      e = (Jb + 0 <= I) ? __expf(acc[ir][0] * 0.125f) : 0.f; rs[ir] += e; ev.x = e;
      e = (Jb + 1 <= I) ? __expf(acc[ir][1] * 0.125f) : 0.f; rs[ir] += e; ev.y = e;
      e = (Jb + 2 <= I) ? __expf(acc[ir][2] * 0.125f) : 0.f; rs[ir] += e; ev.z = e;
      e = (Jb + 3 <= I) ? __expf(acc[ir][3] * 0.125f) : 0.f; rs[ir] += e; ev.w = e;
      uint2 pk;
      pk.x = (unsigned)bfr(ev.x) | ((unsigned)bfr(ev.y) << 16);
      pk.y = (unsigned)bfr(ev.z) | ((unsigned)bfr(ev.w) << 16);
      *reinterpret_cast<uint2*>(Aout + (size_t)I * 1024 + Jb) = pk;
    }
  }

  __syncthreads();
#pragma unroll
  for (int ir = 0; ir < 4; ++ir) red[4 * ti + ir][tj] = rs[ir];
  __syncthreads();
  if (tid < 64) {
    float s = 0.f;
#pragma unroll
    for (int t2 = 0; t2 < 16; ++t2) s += red[tid][t2];
    invs[sys * 1024 + it * 64 + tid] = 1.0f / s;
  }
}

// ---------------------------------------------------------------------------
// K3a: invert each (I + S*L_kk) diagonal block IN PLACE over bf16 A. (unchanged)
// ---------------------------------------------------------------------------
__global__ __launch_bounds__(256) void diaginv_kernel(
    u16* __restrict__ A, const float* __restrict__ invs) {
  const int k = blockIdx.x, sys = blockIdx.y;
  const int tid = threadIdx.x;
  const int r = tid & 63, cq = tid >> 6;

  u16* Ab = A + ((size_t)sys << 20) + (size_t)(k * 64) * 1024 + k * 64;

  __shared__ float Lt[64][65];
  __shared__ float W[64][65];
  __shared__ float sv[64];

#pragma unroll
  for (int m = 0; m < 2; ++m) {
    int f = m * 256 + tid;
    int rr = f >> 3, ch = f & 7;
    uint4 v = *reinterpret_cast<const uint4*>(Ab + (size_t)rr * 1024 + ch * 8);
    float* dst = &Lt[rr][ch * 8];
    dst[0] = bflo(v.x); dst[1] = bfhi(v.x); dst[2] = bflo(v.y); dst[3] = bfhi(v.y);
    dst[4] = bflo(v.z); dst[5] = bfhi(v.z); dst[6] = bflo(v.w); dst[7] = bfhi(v.w);
  }
  if (tid < 64) sv[tid] = invs[sys * 1024 + k * 64 + tid];
#pragma unroll
  for (int c = 0; c < 16; ++c) W[r][cq * 16 + c] = (r == cq * 16 + c) ? 1.f : 0.f;
  __syncthreads();

  for (int r2 = 0; r2 < 64; ++r2) {
    float dinv = 1.0f / (1.0f + sv[r2] * Lt[r2][r2]);
    if (r == r2) {
#pragma unroll
      for (int c = 0; c < 16; ++c) W[r2][cq * 16 + c] *= dinv;
    }
    __syncthreads();
    if (r > r2) {
      float f = sv[r] * Lt[r][r2];
#pragma unroll
      for (int c = 0; c < 16; ++c) W[r][cq * 16 + c] -= f * W[r2][cq * 16 + c];
    }
    __syncthreads();
  }

#pragma unroll
  for (int m = 0; m < 8; ++m) {
    int f = m * 256 + tid;
    int rr = f >> 5, cp = (f & 31) * 2;
    unsigned pk = (unsigned)bfr(W[rr][cp]) | ((unsigned)bfr(W[rr][cp + 1]) << 16);
    *reinterpret_cast<unsigned*>(Ab + (size_t)rr * 1024 + cp) = pk;
  }
}

// ---------------------------------------------------------------------------
// K3b: forward solve. Grid dim3(16 sys, 8 cg), 512 threads (8 waves, 2/SIMD).
// Thread (r = w*8 + l>>3, c = l&7): one (row, col) item; wave covers 8 rows
// x 8 cols -> A-row reads are 8-way broadcast (128B/instr, bank-exact).
// Reg-staged double-buffered A-tile, XOR-swizzled float4 slots.
// ---------------------------------------------------------------------------
__global__ __launch_bounds__(512) void solve_strip_kernel(
    const u16* __restrict__ A, const float* __restrict__ invs,
    const float* __restrict__ Vt, float* __restrict__ Y) {
  const int sys = blockIdx.x, cg = blockIdx.y;
  const int b = sys >> 3, kvh = (sys & 7) >> 1;
  const int tid = threadIdx.x;
  const int r = (tid >> 6) * 8 + ((tid & 63) >> 3);  // 0..63
  const int c = tid & 7;                             // 0..7
  const int c0 = cg * 8;

  const u16* Ab = A + ((size_t)sys << 20);
  const float* Vb = Vt + ((size_t)(b * KVHN + kvh) * TT) * 64;
  float* Yg = Y + (size_t)sys * TT * 64;

  __shared__ float At[2][64][64];  // XOR-swizzled float4 slots
  __shared__ float Yt[8][1028];    // [col][row], stride 1028 -> bank 4c
  __shared__ float uT[8][68];

  const int rr0 = tid >> 3, ch = tid & 7;  // staging: one uint4 per thread

  uint4 vA;
  auto issueL = [&](int kk, int jt) {
    vA = *reinterpret_cast<const uint4*>(
        Ab + (size_t)(kk * 64 + rr0) * 1024 + jt * 64 + ch * 8);
  };
  auto commitL = [&](int buf) {
    const int rl = rr0 & 15;
    float4 lo, hi;
    lo.x = bflo(vA.x); lo.y = bfhi(vA.x); lo.z = bflo(vA.y); lo.w = bfhi(vA.y);
    hi.x = bflo(vA.z); hi.y = bfhi(vA.z); hi.z = bflo(vA.w); hi.w = bfhi(vA.w);
    *reinterpret_cast<float4*>(&At[buf][rr0][((2 * ch) ^ rl) << 2]) = lo;
    *reinterpret_cast<float4*>(&At[buf][rr0][((2 * ch + 1) ^ rl) << 2]) = hi;
  };

  int cur = 0;
  issueL(0, 0);
  commitL(0);

  for (int k = 0; k < 16; ++k) {
    const float sinv = invs[sys * 1024 + k * 64 + r];
    const float v0 = Vb[(size_t)(k * 64 + r) * 64 + c0 + c];
    float acc = 0.f;

    for (int jt = 0; jt <= k; ++jt) {
      __syncthreads();  // publish At[cur]; prior-stage readers done
      const bool last = (k == 15) && (jt == 15);
      if (!last) issueL((jt == k) ? k + 1 : k, (jt == k) ? 0 : jt + 1);

      if (jt < k) {
        const float* Ya = &Yt[c][jt * 64];
#pragma unroll
        for (int c4 = 0; c4 < 16; ++c4) {
          float4 a = *reinterpret_cast<const float4*>(
              &At[cur][r][(c4 ^ (r & 15)) << 2]);
          float4 y = *reinterpret_cast<const float4*>(Ya + (c4 << 2));
          acc += a.x * y.x + a.y * y.y + a.z * y.z + a.w * y.w;
        }
      } else {
        float u = v0 - sinv * acc;
        uT[c][r] = u;
        __syncthreads();  // uT cross-wave (col spans all waves)
        float y = 0.f;
#pragma unroll
        for (int c4 = 0; c4 < 16; ++c4) {
          float4 a = *reinterpret_cast<const float4*>(
              &At[cur][r][(c4 ^ (r & 15)) << 2]);
          float4 u4 = *reinterpret_cast<const float4*>(&uT[c][c4 << 2]);
          y += a.x * u4.x + a.y * u4.y + a.z * u4.z + a.w * u4.w;
        }
        Yt[c][k * 64 + r] = y;
        Yg[(size_t)(k * 64 + r) * 64 + c0 + c] = y;
      }
      if (!last) {
        commitL(cur ^ 1);
        cur ^= 1;
      }
    }
  }
}

// ---------------------------------------------------------------------------
// K4: out = x + Y2d @ Wo as tiled GEMM. Grid (32, 8), 256 threads.
// ---------------------------------------------------------------------------
__global__ __launch_bounds__(256) void out_proj_kernel(
    const float* __restrict__ Y, const float* __restrict__ x,
    const float* __restrict__ Wo, float* __restrict__ out) {
  const int bx = blockIdx.x, by = blockIdx.y;
  const int tid = threadIdx.x;
  const int ti = tid >> 4, tj = tid & 15;
  const int m0 = bx * 64, n0 = by * 64;

  __shared__ float Ys[64][68];
  __shared__ float Ws[64][68];

  float acc[4][4] = {};

  for (int k0 = 0; k0 < 512; k0 += 64) {
    const int h = k0 >> 6;
    __syncthreads();
#pragma unroll
    for (int m = 0; m < 4; ++m) {
      int f = m * 256 + tid;
      int rr = f >> 4, dc = (f & 15) * 4;
      int row = m0 + rr, b = row >> 10, t = row & 1023;
      *reinterpret_cast<float4*>(&Ys[rr][dc]) =
          *reinterpret_cast<const float4*>(
              Y + ((size_t)(b * HH + h) * TT + t) * 64 + dc);
    }
#pragma unroll
    for (int m = 0; m < 4; ++m) {
      int f = m * 256 + tid;
      int rr = f >> 4, dc = (f & 15) * 4;
      *reinterpret_cast<float4*>(&Ws[rr][dc]) =
          *reinterpret_cast<const float4*>(Wo + (size_t)(k0 + rr) * 512 + n0 + dc);
    }
    __syncthreads();

    for (int d = 0; d < 64; d += 4) {
      float4 wv[4];
#pragma unroll
      for (int dd = 0; dd < 4; ++dd)
        wv[dd] = *reinterpret_cast<const float4*>(&Ws[d + dd][4 * tj]);
#pragma unroll
      for (int i2 = 0; i2 < 4; ++i2) {
        float4 xv = *reinterpret_cast<const float4*>(&Ys[4 * ti + i2][d]);
        acc[i2][0] += xv.x * wv[0].x + xv.y * wv[1].x + xv.z * wv[2].x + xv.w * wv[3].x;
        acc[i2][1] += xv.x * wv[0].y + xv.y * wv[1].y + xv.z * wv[2].y + xv.w * wv[3].y;
        acc[i2][2] += xv.x * wv[0].z + xv.y * wv[1].z + xv.z * wv[2].z + xv.w * wv[3].z;
        acc[i2][3] += xv.x * wv[0].w + xv.y * wv[1].w + xv.z * wv[2].w + xv.w * wv[3].w;
      }
    }
  }

#pragma unroll
  for (int i2 = 0; i2 < 4; ++i2) {
    size_t row = (size_t)(m0 + 4 * ti + i2);
    float4 xr = *reinterpret_cast<const float4*>(x + row * 512 + n0 + 4 * tj);
    float4 v;
    v.x = xr.x + acc[i2][0]; v.y = xr.y + acc[i2][1];
    v.z = xr.z + acc[i2][2]; v.w = xr.w + acc[i2][3];
    *reinterpret_cast<float4*>(out + row * 512 + n0 + 4 * tj) = v;
  }
}

// ---------------------------------------------------------------------------
extern "C" void kernel_launch(void* const* d_in, const int* in_sizes, int n_in,
                              void* d_out, int out_size, void* d_ws,
                              size_t ws_size, hipStream_t stream) {
  (void)in_sizes; (void)n_in; (void)out_size; (void)ws_size;
  const float* x = (const float*)d_in[0];
  const float* cosb = (const float*)d_in[1];
  const float* sinb = (const float*)d_in[2];
  const float* Wq = (const float*)d_in[3];
  const float* Wk = (const float*)d_in[4];
  const float* Wv = (const float*)d_in[5];
  const float* Wo = (const float*)d_in[6];
  float* out = (float*)d_out;

  float* ws = (float*)d_ws;
  float* Q = ws;                        // 1,048,576 f
  float* Kt = Q + (size_t)1048576;      //   524,288 f
  float* Vt = Kt + (size_t)524288;      //   524,288 f
  float* Yb = Vt + (size_t)524288;      // 1,048,576 f
  float* invs = Yb + (size_t)1048576;   //    16,384 f
  u16* A = (u16*)(invs + 16384);        // 16,777,216 bf16 = 32 MB

  qkv_kernel<<<dim3(32, 16), 256, 0, stream>>>(x, cosb, sinb, Wq, Wk, Wv, Q, Kt, Vt);
  logits_exp_kernel<<<dim3(16, 16), 256, 0, stream>>>(Q, Kt, A, invs);
  diaginv_kernel<<<dim3(16, 16), 256, 0, stream>>>(A, invs);
  solve_strip_kernel<<<dim3(16, 8), 512, 0, stream>>>(A, invs, Vt, Yb);
  out_proj_kernel<<<dim3(32, 8), 256, 0, stream>>>(Yb, x, Wo, out);
}